// Round 3
// baseline (256.937 us; speedup 1.0000x reference)
//
#include <hip/hip_runtime.h>

#define N_NODES 50000
#define N_EDGES 800000
#define NUM_GRAPHS 16
#define NUM_CLASSES 247
#define SCAN_BLOCKS ((N_NODES + 255) / 256)  // 196
#define CSR_CAP (N_EDGES + 7 * N_NODES)      // degrees padded to multiples of 8

typedef __attribute__((ext_vector_type(8))) short bf16x8;
typedef __attribute__((ext_vector_type(4))) float f32x4;

static inline int nblk(long n) { return (int)((n + 255) / 256); }

__device__ __forceinline__ float bfl(unsigned short u) {
    return __uint_as_float((unsigned)u << 16);
}
__device__ __forceinline__ unsigned short bf16_rne(float f) {
    unsigned u = __float_as_uint(f);
    u += 0x7FFF + ((u >> 16) & 1);
    return (unsigned short)(u >> 16);
}

// ---- degree histogram into 8 XCD-local copies; returns rank within copy ----
__global__ void k_deg(const int* __restrict__ col, int* __restrict__ degc,
                      int* __restrict__ pos, int E) {
    int e = blockIdx.x * blockDim.x + threadIdx.x;
    if (e >= E) return;
    int c8 = (e >> 8) & 7;
    pos[e] = atomicAdd(&degc[c8 * N_NODES + col[e]], 1);
}

// ---- scan phase 1: per-block exclusive scan of PADDED degree + batch hist --
__global__ __launch_bounds__(256) void k_scan1(const int* __restrict__ degc,
                                               int* __restrict__ rowptr,
                                               int* __restrict__ bsum,
                                               const int* __restrict__ batch,
                                               float* __restrict__ pcnt, int N) {
    __shared__ int buf[256];
    __shared__ int hist[NUM_GRAPHS];
    int t = threadIdx.x;
    if (t < NUM_GRAPHS) hist[t] = 0;
    __syncthreads();  // hist must be zeroed before any wave's atomicAdd
    int i = blockIdx.x * 256 + t;
    int v = 0;
    if (i < N) {
        int tot = 0;
#pragma unroll
        for (int c = 0; c < 8; ++c) tot += degc[c * N_NODES + i];
        v = (tot + 7) & ~7;  // padded degree
        atomicAdd(&hist[batch[i]], 1);
    }
    buf[t] = v;
    __syncthreads();
#pragma unroll
    for (int off = 1; off < 256; off <<= 1) {
        int tmp = (t >= off) ? buf[t - off] : 0;
        __syncthreads();
        if (t >= off) buf[t] += tmp;
        __syncthreads();
    }
    if (i < N) rowptr[i] = buf[t] - v;  // exclusive within block
    if (t == 255) bsum[blockIdx.x] = buf[255];
    if (t < NUM_GRAPHS && hist[t] > 0) atomicAdd(&pcnt[t], (float)hist[t]);
}

// ---- scan phase 2 (folded): block-offset + per-copy bases + dinv + xs + Wt
//      + sentinel-fill of the pad slots + rowptr[N] --------------------------
__global__ __launch_bounds__(256) void k_scan3(int* __restrict__ rowptr,
                                               const int* __restrict__ bsum,
                                               const int* __restrict__ degc,
                                               int* __restrict__ base,
                                               float* __restrict__ dinv,
                                               const float* __restrict__ x,
                                               float* __restrict__ xs,
                                               int* __restrict__ csr,
                                               const float* __restrict__ W2,
                                               const float* __restrict__ W3,
                                               unsigned short* __restrict__ Wt2,
                                               unsigned short* __restrict__ Wt3,
                                               int N) {
    __shared__ int red[256];
    int t = threadIdx.x;
    int b = blockIdx.x;
    red[t] = (t < b) ? bsum[t] : 0;  // b <= 195 < 256
    __syncthreads();
#pragma unroll
    for (int off = 128; off > 0; off >>= 1) {
        if (t < off) red[t] += red[t + off];
        __syncthreads();
    }
    int boff = red[0];
    int i = b * 256 + t;
    if (i < N) {
        int rp = rowptr[i] + boff;
        rowptr[i] = rp;
        int run = rp, tot = 0;
#pragma unroll
        for (int c = 0; c < 8; ++c) {
            int d = degc[c * N_NODES + i];
            base[c * N_NODES + i] = run;
            run += d;
            tot += d;
        }
        int pdeg = (tot + 7) & ~7;
        // sentinel-fill pad slots -> point at the all-zero row N_NODES
        for (int j = rp + tot; j < rp + pdeg; ++j) csr[j] = N_NODES;
        if (i == N - 1) rowptr[N] = rp + pdeg;  // padded total
        float dv = rsqrtf((float)tot + 1.0f);   // +1 = self loop
        dinv[i] = dv;
        xs[i * 3 + 0] = dv * x[i * 3 + 0];
        xs[i * 3 + 1] = dv * x[i * 3 + 1];
        xs[i * 3 + 2] = dv * x[i * 3 + 2];
    }
    if (i == 0) {  // zero sentinel row of xs
        xs[3 * N_NODES + 0] = 0.0f;
        xs[3 * N_NODES + 1] = 0.0f;
        xs[3 * N_NODES + 2] = 0.0f;
    }
    // folded weight cast+transpose
    if (i < 64 * 128) {                       // Wt2: [f=128][k=64]
        int f = i / 64, k = i % 64;
        Wt2[i] = bf16_rne(W2[k * 128 + f]);
    } else if (i < 64 * 128 + 128 * 256) {    // Wt3: [f=256][k=128]
        int j = i - 64 * 128;
        int f = j / 128, k = j % 128;
        Wt3[j] = bf16_rne(W3[k * 256 + f]);
    }
}

// ---- CSR fill: no atomic; slot = base[copy][dst] + rank-within-copy --------
__global__ void k_fill(const int* __restrict__ row, const int* __restrict__ col,
                       const int* __restrict__ base, const int* __restrict__ pos,
                       int* __restrict__ csr_src, int E) {
    int e = blockIdx.x * blockDim.x + threadIdx.x;
    if (e >= E) return;
    int c8 = (e >> 8) & 7;
    csr_src[base[c8 * N_NODES + col[e]] + pos[e]] = row[e];
}

// ---- fused layer 1: p1 = dv*(xs[v]+Σxs[r]); h1' = dv*relu(p1 W1 + b1) ------
__global__ void k_layer1(const float* __restrict__ xs, const float* __restrict__ dinv,
                         const int* __restrict__ rowptr, const int* __restrict__ csr_src,
                         const float* __restrict__ W1, const float* __restrict__ b1,
                         unsigned short* __restrict__ out, int N) {
    int v = blockIdx.x * blockDim.x + threadIdx.x;
    if (v >= N) return;
    float a0 = xs[v * 3 + 0];
    float a1 = xs[v * 3 + 1];
    float a2 = xs[v * 3 + 2];
    int j = rowptr[v];
    int j1 = rowptr[v + 1];
    for (; j + 4 <= j1; j += 4) {
        int r0 = csr_src[j + 0], r1 = csr_src[j + 1];
        int r2 = csr_src[j + 2], r3 = csr_src[j + 3];
        float x00 = xs[r0 * 3 + 0], x01 = xs[r0 * 3 + 1], x02 = xs[r0 * 3 + 2];
        float x10 = xs[r1 * 3 + 0], x11 = xs[r1 * 3 + 1], x12 = xs[r1 * 3 + 2];
        float x20 = xs[r2 * 3 + 0], x21 = xs[r2 * 3 + 1], x22 = xs[r2 * 3 + 2];
        float x30 = xs[r3 * 3 + 0], x31 = xs[r3 * 3 + 1], x32 = xs[r3 * 3 + 2];
        a0 += x00; a1 += x01; a2 += x02;
        a0 += x10; a1 += x11; a2 += x12;
        a0 += x20; a1 += x21; a2 += x22;
        a0 += x30; a1 += x31; a2 += x32;
    }
    for (; j < j1; ++j) {  // dead with padded degrees
        int r = csr_src[j];
        a0 += xs[r * 3 + 0];
        a1 += xs[r * 3 + 1];
        a2 += xs[r * 3 + 2];
    }
    float dv = dinv[v];
    float p0 = dv * a0, p1 = dv * a1, p2 = dv * a2;
    unsigned short* ov = out + (long)v * 64;
#pragma unroll
    for (int f = 0; f < 64; f += 2) {
        float s0 = fmaf(p0, W1[f],     fmaf(p1, W1[64 + f],     fmaf(p2, W1[128 + f],     b1[f])));
        float s1 = fmaf(p0, W1[f + 1], fmaf(p1, W1[64 + f + 1], fmaf(p2, W1[128 + f + 1], b1[f + 1])));
        s0 = fmaxf(s0, 0.0f) * dv;  // pre-scale for next prop
        s1 = fmaxf(s1, 0.0f) * dv;
        unsigned pk = (unsigned)bf16_rne(s0) | ((unsigned)bf16_rne(s1) << 16);
        *(unsigned*)(ov + f) = pk;
    }
}

// ---- FUSED prop + MFMA GEMM per 16-row m-tile; optional fused mean-pool ----
// R2 change: 2 waves per block (128 thr) instead of 4. Each wave handles 8
// rows (4 pr-pairs; inner gather loops verbatim) and 2x f-tiles in phase 2.
// Rationale: 4-wave blocks cap device concurrency at 2048 blocks -> 3125
// blocks = 1.5 "generations" (OccupancyPercent 60). 2-wave blocks allow 4096
// concurrent -> single generation, and double per-CU loads-in-flight. This is
// the A/B for MSHR-rate vs concurrency bound.
template <int K, int F, bool PRESCALE, bool POOL>
__global__ __launch_bounds__(128) void k_fused(
        const unsigned short* __restrict__ h, const float* __restrict__ dinv,
        const int* __restrict__ rowptr, const int* __restrict__ csr_src,
        const unsigned short* __restrict__ Wt, const float* __restrict__ b,
        unsigned short* __restrict__ out, const int* __restrict__ batch,
        float* __restrict__ psum, int N) {
    constexpr int NF = F / 16;    // f-tiles: 8 (F=128) / 16 (F=256)
    constexpr int FPW = NF / 2;   // f-tiles per wave (2 waves): 4 / 8
    constexpr int KB = K / 32;    // k-blocks: 2 / 4
    constexpr int KL = K / 64;    // features per lane in prop: 1 / 2
    constexpr int PADK = K + 8;
    __shared__ unsigned short plds[16][PADK];
    int wave = threadIdx.x >> 6;  // 0..1
    int lane = threadIdx.x & 63;
    int m0 = blockIdx.x * 16;

    // ---- phase 1: propagation into LDS, rows processed in pairs ----
    for (int pr = 0; pr < 4; ++pr) {
        int va = m0 + wave * 8 + pr * 2;
        int vb = va + 1;
        float acca[KL], accb[KL];
        const unsigned short* hva = h + (long)va * K + lane * KL;
        const unsigned short* hvb = h + (long)vb * K + lane * KL;
        if (KL == 2) {
            unsigned ua = *(const unsigned*)hva;
            unsigned ub = *(const unsigned*)hvb;
            acca[0] = __uint_as_float(ua << 16);
            acca[1] = __uint_as_float(ua & 0xFFFF0000u);
            accb[0] = __uint_as_float(ub << 16);
            accb[1] = __uint_as_float(ub & 0xFFFF0000u);
        } else {
            acca[0] = bfl(hva[0]);
            accb[0] = bfl(hvb[0]);
        }
        int ja  = __builtin_amdgcn_readfirstlane(rowptr[va]);
        int j1a = __builtin_amdgcn_readfirstlane(rowptr[va + 1]);
        int jb  = j1a;
        int j1b = __builtin_amdgcn_readfirstlane(rowptr[vb + 1]);
        while (ja + 8 <= j1a && jb + 8 <= j1b) {
            int ra[8], rb[8];
#pragma unroll
            for (int u = 0; u < 8; ++u) ra[u] = csr_src[ja + u];
#pragma unroll
            for (int u = 0; u < 8; ++u) rb[u] = csr_src[jb + u];
            if (KL == 2) {
                unsigned ta[8], tb[8];
#pragma unroll
                for (int u = 0; u < 8; ++u)
                    ta[u] = *(const unsigned*)(h + (long)ra[u] * K + lane * 2);
#pragma unroll
                for (int u = 0; u < 8; ++u)
                    tb[u] = *(const unsigned*)(h + (long)rb[u] * K + lane * 2);
#pragma unroll
                for (int u = 0; u < 8; ++u) {
                    acca[0] += __uint_as_float(ta[u] << 16);
                    acca[1] += __uint_as_float(ta[u] & 0xFFFF0000u);
                }
#pragma unroll
                for (int u = 0; u < 8; ++u) {
                    accb[0] += __uint_as_float(tb[u] << 16);
                    accb[1] += __uint_as_float(tb[u] & 0xFFFF0000u);
                }
            } else {
                unsigned short ta[8], tb[8];
#pragma unroll
                for (int u = 0; u < 8; ++u) ta[u] = h[(long)ra[u] * K + lane];
#pragma unroll
                for (int u = 0; u < 8; ++u) tb[u] = h[(long)rb[u] * K + lane];
#pragma unroll
                for (int u = 0; u < 8; ++u) acca[0] += bfl(ta[u]);
#pragma unroll
                for (int u = 0; u < 8; ++u) accb[0] += bfl(tb[u]);
            }
            ja += 8;
            jb += 8;
        }
        for (; ja + 8 <= j1a; ja += 8) {
            int r[8];
#pragma unroll
            for (int u = 0; u < 8; ++u) r[u] = csr_src[ja + u];
            if (KL == 2) {
                unsigned tv[8];
#pragma unroll
                for (int u = 0; u < 8; ++u)
                    tv[u] = *(const unsigned*)(h + (long)r[u] * K + lane * 2);
#pragma unroll
                for (int u = 0; u < 8; ++u) {
                    acca[0] += __uint_as_float(tv[u] << 16);
                    acca[1] += __uint_as_float(tv[u] & 0xFFFF0000u);
                }
            } else {
                unsigned short tv[8];
#pragma unroll
                for (int u = 0; u < 8; ++u) tv[u] = h[(long)r[u] * K + lane];
#pragma unroll
                for (int u = 0; u < 8; ++u) acca[0] += bfl(tv[u]);
            }
        }
        for (; ja < j1a; ++ja) {  // dead with padded degrees
            int r = csr_src[ja];
            if (KL == 2) {
                unsigned u = *(const unsigned*)(h + (long)r * K + lane * 2);
                acca[0] += __uint_as_float(u << 16);
                acca[1] += __uint_as_float(u & 0xFFFF0000u);
            } else {
                acca[0] += bfl(h[(long)r * K + lane]);
            }
        }
        for (; jb + 8 <= j1b; jb += 8) {
            int r[8];
#pragma unroll
            for (int u = 0; u < 8; ++u) r[u] = csr_src[jb + u];
            if (KL == 2) {
                unsigned tv[8];
#pragma unroll
                for (int u = 0; u < 8; ++u)
                    tv[u] = *(const unsigned*)(h + (long)r[u] * K + lane * 2);
#pragma unroll
                for (int u = 0; u < 8; ++u) {
                    accb[0] += __uint_as_float(tv[u] << 16);
                    accb[1] += __uint_as_float(tv[u] & 0xFFFF0000u);
                }
            } else {
                unsigned short tv[8];
#pragma unroll
                for (int u = 0; u < 8; ++u) tv[u] = h[(long)r[u] * K + lane];
#pragma unroll
                for (int u = 0; u < 8; ++u) accb[0] += bfl(tv[u]);
            }
        }
        for (; jb < j1b; ++jb) {  // dead with padded degrees
            int r = csr_src[jb];
            if (KL == 2) {
                unsigned u = *(const unsigned*)(h + (long)r * K + lane * 2);
                accb[0] += __uint_as_float(u << 16);
                accb[1] += __uint_as_float(u & 0xFFFF0000u);
            } else {
                accb[0] += bfl(h[(long)r * K + lane]);
            }
        }
        float da = dinv[va];
        float db = dinv[vb];
        int rla = wave * 8 + pr * 2;
        if (KL == 2) {
            unsigned pa = (unsigned)bf16_rne(da * acca[0]) | ((unsigned)bf16_rne(da * acca[1]) << 16);
            unsigned pb = (unsigned)bf16_rne(db * accb[0]) | ((unsigned)bf16_rne(db * accb[1]) << 16);
            *(unsigned*)&plds[rla][lane * 2] = pa;
            *(unsigned*)&plds[rla + 1][lane * 2] = pb;
        } else {
            plds[rla][lane] = bf16_rne(da * acca[0]);
            plds[rla + 1][lane] = bf16_rne(db * accb[0]);
        }
    }
    __syncthreads();

    // ---- phase 2: MFMA (layout verified R9/R11) ----
    int quad = lane >> 4;
    int l16 = lane & 15;
    bf16x8 afr[KB];
#pragma unroll
    for (int kb = 0; kb < KB; ++kb)
        afr[kb] = *(const bf16x8*)(const void*)&plds[l16][kb * 32 + quad * 8];
#pragma unroll
    for (int fi = 0; fi < FPW; ++fi) {
        int f0 = (wave * FPW + fi) * 16;
        const unsigned short* wrow = Wt + (long)(f0 + l16) * K + quad * 8;
        f32x4 acc4 = {0.f, 0.f, 0.f, 0.f};
#pragma unroll
        for (int kb = 0; kb < KB; ++kb) {
            bf16x8 bb = *(const bf16x8*)(const void*)(wrow + kb * 32);
            acc4 = __builtin_amdgcn_mfma_f32_16x16x32_bf16(afr[kb], bb, acc4, 0, 0, 0);
        }
        float bias = b[f0 + l16];
        if (POOL) {
            int g0 = batch[m0];
            int g15 = batch[m0 + 15];
            if (g0 == g15) {  // uniform block (all but ~15 of 3125)
                float s = fmaxf(acc4[0] + bias, 0.0f);
                s += fmaxf(acc4[1] + bias, 0.0f);
                s += fmaxf(acc4[2] + bias, 0.0f);
                s += fmaxf(acc4[3] + bias, 0.0f);
                s += __shfl_xor(s, 16);
                s += __shfl_xor(s, 32);
                if (quad == 0) atomicAdd(&psum[g0 * 256 + f0 + l16], s);
            } else {  // graph boundary inside block: per-element atomics
#pragma unroll
                for (int r = 0; r < 4; ++r) {
                    int m = m0 + quad * 4 + r;
                    float val = fmaxf(acc4[r] + bias, 0.0f);
                    atomicAdd(&psum[batch[m] * 256 + f0 + l16], val);
                }
            }
        } else {
#pragma unroll
            for (int r = 0; r < 4; ++r) {
                int m = m0 + quad * 4 + r;
                float val = fmaxf(acc4[r] + bias, 0.0f);
                if (PRESCALE) val *= dinv[m];
                out[(long)m * F + f0 + l16] = bf16_rne(val);
            }
        }
    }
}

// ---- final FC --------------------------------------------------------------
__global__ void k_fc(const float* __restrict__ psum, const float* __restrict__ pcnt,
                     const float* __restrict__ Wfc, const float* __restrict__ bfc,
                     float* __restrict__ out) {
    int tid = blockIdx.x * blockDim.x + threadIdx.x;
    if (tid >= NUM_GRAPHS * NUM_CLASSES) return;
    int g = tid / NUM_CLASSES;
    int c = tid % NUM_CLASSES;
    float s = 0.0f;
#pragma unroll 8
    for (int k = 0; k < 256; ++k) s = fmaf(psum[g * 256 + k], Wfc[k * NUM_CLASSES + c], s);
    float cnt = pcnt[g];
    cnt = cnt > 1.0f ? cnt : 1.0f;
    out[tid] = s / cnt + bfc[c];
}

extern "C" void kernel_launch(void* const* d_in, const int* in_sizes, int n_in,
                              void* d_out, int out_size, void* d_ws, size_t ws_size,
                              hipStream_t stream) {
    const float* x     = (const float*)d_in[0];
    const int*   ei    = (const int*)d_in[1];
    const int*   batch = (const int*)d_in[2];
    const float* W1    = (const float*)d_in[3];
    const float* b1    = (const float*)d_in[4];
    const float* W2    = (const float*)d_in[5];
    const float* b2    = (const float*)d_in[6];
    const float* W3    = (const float*)d_in[7];
    const float* b3    = (const float*)d_in[8];
    const float* Wfc   = (const float*)d_in[9];
    const float* bfc   = (const float*)d_in[10];
    float* out = (float*)d_out;

    const int* row = ei;            // src
    const int* col = ei + N_EDGES;  // dst

    // workspace layout, bf16 arrays 16B-aligned; sentinel row at index N_NODES
    float*  xs   = (float*)d_ws;                         // (N+1)*3 f32 (+pad to 150004 for alignment)
    float*  dinv = xs + 150004;                          // N
    float*  psum = dinv + N_NODES;                       // 16*256
    float*  pcnt = psum + NUM_GRAPHS * 256;              // 16
    unsigned short* X   = (unsigned short*)(pcnt + NUM_GRAPHS);  // (N+1)*64 bf16 (h1')
    unsigned short* Y   = X + (size_t)(N_NODES + 1) * 64;        // (N+1)*128 bf16 (h2')
    unsigned short* Wt2 = Y + (size_t)(N_NODES + 1) * 128;       // 128*64
    unsigned short* Wt3 = Wt2 + 128 * 64;                        // 256*128
    int* degc   = (int*)(Wt3 + 256 * 128);               // 8*N (XCD-local copies)
    int* base   = degc + 8 * N_NODES;                    // 8*N (per-copy slot bases)
    int* rowptr = base + 8 * N_NODES;                    // N+1
    int* csrsrc = rowptr + N_NODES + 1;                  // CSR_CAP (padded)
    int* pos    = csrsrc + CSR_CAP;                      // E
    int* bsum   = pos + N_EDGES;                         // SCAN_BLOCKS

    hipMemsetAsync(degc, 0, 8 * N_NODES * sizeof(int), stream);
    hipMemsetAsync(psum, 0, (NUM_GRAPHS * 256 + NUM_GRAPHS) * sizeof(float), stream);
    // zero sentinel rows of X / Y (read by padded gather slots)
    hipMemsetAsync(X + (size_t)N_NODES * 64, 0, 64 * sizeof(unsigned short), stream);
    hipMemsetAsync(Y + (size_t)N_NODES * 128, 0, 128 * sizeof(unsigned short), stream);

    // ---- CSR build + norms + pre-scaled x + weight casts ----
    k_deg<<<nblk(N_EDGES), 256, 0, stream>>>(col, degc, pos, N_EDGES);
    k_scan1<<<SCAN_BLOCKS, 256, 0, stream>>>(degc, rowptr, bsum, batch, pcnt, N_NODES);
    k_scan3<<<SCAN_BLOCKS, 256, 0, stream>>>(rowptr, bsum, degc, base, dinv, x, xs,
                                             csrsrc, W2, W3, Wt2, Wt3, N_NODES);
    k_fill<<<nblk(N_EDGES), 256, 0, stream>>>(row, col, base, pos, csrsrc, N_EDGES);

    // ---- layer 1 (fused prop+linear): X = h1' = d*relu((A~x)W1+b1), bf16 ---
    k_layer1<<<nblk(N_NODES), 256, 0, stream>>>(xs, dinv, rowptr, csrsrc, W1, b1, X, N_NODES);

    int mtiles = N_NODES / 16;  // 3125, exact

    // ---- layer 2 fused: Y = h2' = d*relu((A~-apply X) W2 + b2) -------------
    k_fused<64, 128, true, false><<<mtiles, 128, 0, stream>>>(
        X, dinv, rowptr, csrsrc, Wt2, b2, Y, batch, psum, N_NODES);

    // ---- layer 3 fused + POOL: psum += relu((A~-apply Y) W3 + b3) ----------
    k_fused<128, 256, false, true><<<mtiles, 128, 0, stream>>>(
        Y, dinv, rowptr, csrsrc, Wt3, b3, (unsigned short*)nullptr, batch, psum, N_NODES);

    // ---- FC ----
    k_fc<<<nblk(NUM_GRAPHS * NUM_CLASSES), 256, 0, stream>>>(psum, pcnt, Wfc, bfc, out);
}

// Round 4
// 245.802 us; speedup vs baseline: 1.0453x; 1.0453x over previous
//
#include <hip/hip_runtime.h>

#define N_NODES 50000
#define N_EDGES 800000
#define NUM_GRAPHS 16
#define NUM_CLASSES 247
#define SCAN_BLOCKS ((N_NODES + 255) / 256)  // 196
#define CSR_CAP (N_EDGES + 7 * N_NODES)      // degrees padded to multiples of 8

typedef __attribute__((ext_vector_type(8))) short bf16x8;
typedef __attribute__((ext_vector_type(4))) float f32x4;

static inline int nblk(long n) { return (int)((n + 255) / 256); }

__device__ __forceinline__ float bfl(unsigned short u) {
    return __uint_as_float((unsigned)u << 16);
}
__device__ __forceinline__ unsigned short bf16_rne(float f) {
    unsigned u = __float_as_uint(f);
    u += 0x7FFF + ((u >> 16) & 1);
    return (unsigned short)(u >> 16);
}

// ---- unsigned e4m4 (bias 7) quantization for post-ReLU activations --------
// Stored values carry a x64 scale shift (folded into producer epilogue);
// Wt2/Wt3 are pre-divided by 64 so the GEMM result is true-scale. Range of
// stored values: [2^-6, 496]; smaller -> 0 (err <= 2.4e-4 in true units).
__device__ __forceinline__ unsigned q8(float v) {
    // v >= 0 (post-relu, x64). RNE to 4 mantissa bits, clamp to 255.
    if (v < 0.015625f) return 0u;
    unsigned u = __float_as_uint(v) - (120u << 23);
    u += 0x3FFFF + ((u >> 19) & 1);
    unsigned q = u >> 19;
    return q > 255u ? 255u : q;
}
__device__ __forceinline__ float dq8(unsigned x) {
    // exact inverse for x>=16 (normals); x==0 -> 0. x in [1,15] never emitted.
    float f = __uint_as_float((x + 1920u) << 19);
    return x ? f : 0.0f;
}

// ---- degree histogram into 8 XCD-local copies; returns rank within copy ----
__global__ void k_deg(const int* __restrict__ col, int* __restrict__ degc,
                      int* __restrict__ pos, int E) {
    int e = blockIdx.x * blockDim.x + threadIdx.x;
    if (e >= E) return;
    int c8 = (e >> 8) & 7;
    pos[e] = atomicAdd(&degc[c8 * N_NODES + col[e]], 1);
}

// ---- scan phase 1: per-block exclusive scan of PADDED degree + batch hist --
__global__ __launch_bounds__(256) void k_scan1(const int* __restrict__ degc,
                                               int* __restrict__ rowptr,
                                               int* __restrict__ bsum,
                                               const int* __restrict__ batch,
                                               float* __restrict__ pcnt, int N) {
    __shared__ int buf[256];
    __shared__ int hist[NUM_GRAPHS];
    int t = threadIdx.x;
    if (t < NUM_GRAPHS) hist[t] = 0;
    __syncthreads();  // hist must be zeroed before any wave's atomicAdd
    int i = blockIdx.x * 256 + t;
    int v = 0;
    if (i < N) {
        int tot = 0;
#pragma unroll
        for (int c = 0; c < 8; ++c) tot += degc[c * N_NODES + i];
        v = (tot + 7) & ~7;  // padded degree
        atomicAdd(&hist[batch[i]], 1);
    }
    buf[t] = v;
    __syncthreads();
#pragma unroll
    for (int off = 1; off < 256; off <<= 1) {
        int tmp = (t >= off) ? buf[t - off] : 0;
        __syncthreads();
        if (t >= off) buf[t] += tmp;
        __syncthreads();
    }
    if (i < N) rowptr[i] = buf[t] - v;  // exclusive within block
    if (t == 255) bsum[blockIdx.x] = buf[255];
    if (t < NUM_GRAPHS && hist[t] > 0) atomicAdd(&pcnt[t], (float)hist[t]);
}

// ---- scan phase 2 (folded): block-offset + per-copy bases + dinv + xs + Wt
//      + sentinel-fill of the pad slots + rowptr[N] --------------------------
// Wt2/Wt3 are cast to bf16 with a /64 scale (exact: exponent shift only) to
// compensate the x64 scale shift in the e4m4-quantized activations.
__global__ __launch_bounds__(256) void k_scan3(int* __restrict__ rowptr,
                                               const int* __restrict__ bsum,
                                               const int* __restrict__ degc,
                                               int* __restrict__ base,
                                               float* __restrict__ dinv,
                                               const float* __restrict__ x,
                                               float* __restrict__ xs,
                                               int* __restrict__ csr,
                                               const float* __restrict__ W2,
                                               const float* __restrict__ W3,
                                               unsigned short* __restrict__ Wt2,
                                               unsigned short* __restrict__ Wt3,
                                               int N) {
    __shared__ int red[256];
    int t = threadIdx.x;
    int b = blockIdx.x;
    red[t] = (t < b) ? bsum[t] : 0;  // b <= 195 < 256
    __syncthreads();
#pragma unroll
    for (int off = 128; off > 0; off >>= 1) {
        if (t < off) red[t] += red[t + off];
        __syncthreads();
    }
    int boff = red[0];
    int i = b * 256 + t;
    if (i < N) {
        int rp = rowptr[i] + boff;
        rowptr[i] = rp;
        int run = rp, tot = 0;
#pragma unroll
        for (int c = 0; c < 8; ++c) {
            int d = degc[c * N_NODES + i];
            base[c * N_NODES + i] = run;
            run += d;
            tot += d;
        }
        int pdeg = (tot + 7) & ~7;
        // sentinel-fill pad slots -> point at the all-zero row N_NODES
        for (int j = rp + tot; j < rp + pdeg; ++j) csr[j] = N_NODES;
        if (i == N - 1) rowptr[N] = rp + pdeg;  // padded total
        float dv = rsqrtf((float)tot + 1.0f);   // +1 = self loop
        dinv[i] = dv;
        xs[i * 3 + 0] = dv * x[i * 3 + 0];
        xs[i * 3 + 1] = dv * x[i * 3 + 1];
        xs[i * 3 + 2] = dv * x[i * 3 + 2];
    }
    if (i == 0) {  // zero sentinel row of xs
        xs[3 * N_NODES + 0] = 0.0f;
        xs[3 * N_NODES + 1] = 0.0f;
        xs[3 * N_NODES + 2] = 0.0f;
    }
    // folded weight cast+transpose (with /64 e4m4 scale compensation)
    if (i < 64 * 128) {                       // Wt2: [f=128][k=64]
        int f = i / 64, k = i % 64;
        Wt2[i] = bf16_rne(W2[k * 128 + f] * 0.015625f);
    } else if (i < 64 * 128 + 128 * 256) {    // Wt3: [f=256][k=128]
        int j = i - 64 * 128;
        int f = j / 128, k = j % 128;
        Wt3[j] = bf16_rne(W3[k * 256 + f] * 0.015625f);
    }
}

// ---- CSR fill: no atomic; slot = base[copy][dst] + rank-within-copy --------
__global__ void k_fill(const int* __restrict__ row, const int* __restrict__ col,
                       const int* __restrict__ base, const int* __restrict__ pos,
                       int* __restrict__ csr_src, int E) {
    int e = blockIdx.x * blockDim.x + threadIdx.x;
    if (e >= E) return;
    int c8 = (e >> 8) & 7;
    csr_src[base[c8 * N_NODES + col[e]] + pos[e]] = row[e];
}

// ---- fused layer 1: p1 = dv*(xs[v]+Σxs[r]); X = q8(64*dv*relu(p1 W1 + b1)) -
__global__ void k_layer1(const float* __restrict__ xs, const float* __restrict__ dinv,
                         const int* __restrict__ rowptr, const int* __restrict__ csr_src,
                         const float* __restrict__ W1, const float* __restrict__ b1,
                         unsigned char* __restrict__ out, int N) {
    int v = blockIdx.x * blockDim.x + threadIdx.x;
    if (v >= N) return;
    float a0 = xs[v * 3 + 0];
    float a1 = xs[v * 3 + 1];
    float a2 = xs[v * 3 + 2];
    int j = rowptr[v];
    int j1 = rowptr[v + 1];
    for (; j + 4 <= j1; j += 4) {
        int r0 = csr_src[j + 0], r1 = csr_src[j + 1];
        int r2 = csr_src[j + 2], r3 = csr_src[j + 3];
        float x00 = xs[r0 * 3 + 0], x01 = xs[r0 * 3 + 1], x02 = xs[r0 * 3 + 2];
        float x10 = xs[r1 * 3 + 0], x11 = xs[r1 * 3 + 1], x12 = xs[r1 * 3 + 2];
        float x20 = xs[r2 * 3 + 0], x21 = xs[r2 * 3 + 1], x22 = xs[r2 * 3 + 2];
        float x30 = xs[r3 * 3 + 0], x31 = xs[r3 * 3 + 1], x32 = xs[r3 * 3 + 2];
        a0 += x00; a1 += x01; a2 += x02;
        a0 += x10; a1 += x11; a2 += x12;
        a0 += x20; a1 += x21; a2 += x22;
        a0 += x30; a1 += x31; a2 += x32;
    }
    for (; j < j1; ++j) {  // dead with padded degrees
        int r = csr_src[j];
        a0 += xs[r * 3 + 0];
        a1 += xs[r * 3 + 1];
        a2 += xs[r * 3 + 2];
    }
    float dv = dinv[v];
    float p0 = dv * a0, p1 = dv * a1, p2 = dv * a2;
    float dv64 = dv * 64.0f;  // pre-scale for next prop + e4m4 scale shift
    unsigned char* ov = out + (long)v * 64;
#pragma unroll
    for (int f = 0; f < 64; f += 4) {
        unsigned pk = 0;
#pragma unroll
        for (int t = 0; t < 4; ++t) {
            float s = fmaf(p0, W1[f + t], fmaf(p1, W1[64 + f + t], fmaf(p2, W1[128 + f + t], b1[f + t])));
            s = fmaxf(s, 0.0f) * dv64;
            pk |= q8(s) << (8 * t);
        }
        *(unsigned*)(ov + f) = pk;
    }
}

// ---- FUSED prop + MFMA GEMM per 16-row m-tile; optional fused mean-pool ----
// Gather = R15 2-row interleaved structure (4 waves, R2 shape — R3's 2-wave
// variant regressed). Inputs h are unsigned-e4m4 bytes (x64 scale); decode =
// add+shl+cndmask. plds holds bf16 of 64*p; Wt is pre-divided by 64 so MFMA
// output is true-scale. Phase 2 = verified R9/R11 MFMA layout.
template <int K, int F, bool PRESCALE, bool POOL>
__global__ __launch_bounds__(256) void k_fused(
        const unsigned char* __restrict__ h, const float* __restrict__ dinv,
        const int* __restrict__ rowptr, const int* __restrict__ csr_src,
        const unsigned short* __restrict__ Wt, const float* __restrict__ b,
        unsigned char* __restrict__ out, const int* __restrict__ batch,
        float* __restrict__ psum, int N) {
    constexpr int NF = F / 16;    // f-tiles: 8 (F=128) / 16 (F=256)
    constexpr int FPW = NF / 4;   // f-tiles per wave: 2 / 4
    constexpr int KB = K / 32;    // k-blocks: 2 / 4
    constexpr int KL = K / 64;    // features (bytes) per lane in prop: 1 / 2
    constexpr int PADK = K + 8;
    __shared__ unsigned short plds[16][PADK];
    int wave = threadIdx.x >> 6;
    int lane = threadIdx.x & 63;
    int m0 = blockIdx.x * 16;

    // ---- phase 1: propagation into LDS, rows processed in pairs ----
    for (int pr = 0; pr < 2; ++pr) {
        int va = m0 + wave * 4 + pr * 2;
        int vb = va + 1;
        float acca[KL], accb[KL];
        const unsigned char* hva = h + (long)va * K + lane * KL;
        const unsigned char* hvb = h + (long)vb * K + lane * KL;
        if (KL == 2) {
            unsigned ua = *(const unsigned short*)hva;
            unsigned ub = *(const unsigned short*)hvb;
            acca[0] = dq8(ua & 0xff);
            acca[1] = dq8(ua >> 8);
            accb[0] = dq8(ub & 0xff);
            accb[1] = dq8(ub >> 8);
        } else {
            acca[0] = dq8(hva[0]);
            accb[0] = dq8(hvb[0]);
        }
        int ja  = __builtin_amdgcn_readfirstlane(rowptr[va]);
        int j1a = __builtin_amdgcn_readfirstlane(rowptr[va + 1]);
        int jb  = j1a;
        int j1b = __builtin_amdgcn_readfirstlane(rowptr[vb + 1]);
        while (ja + 8 <= j1a && jb + 8 <= j1b) {
            int ra[8], rb[8];
#pragma unroll
            for (int u = 0; u < 8; ++u) ra[u] = csr_src[ja + u];
#pragma unroll
            for (int u = 0; u < 8; ++u) rb[u] = csr_src[jb + u];
            if (KL == 2) {
                unsigned ta[8], tb[8];
#pragma unroll
                for (int u = 0; u < 8; ++u)
                    ta[u] = *(const unsigned short*)(h + (long)ra[u] * K + lane * 2);
#pragma unroll
                for (int u = 0; u < 8; ++u)
                    tb[u] = *(const unsigned short*)(h + (long)rb[u] * K + lane * 2);
#pragma unroll
                for (int u = 0; u < 8; ++u) {
                    acca[0] += dq8(ta[u] & 0xff);
                    acca[1] += dq8(ta[u] >> 8);
                }
#pragma unroll
                for (int u = 0; u < 8; ++u) {
                    accb[0] += dq8(tb[u] & 0xff);
                    accb[1] += dq8(tb[u] >> 8);
                }
            } else {
                unsigned char ta[8], tb[8];
#pragma unroll
                for (int u = 0; u < 8; ++u) ta[u] = h[(long)ra[u] * K + lane];
#pragma unroll
                for (int u = 0; u < 8; ++u) tb[u] = h[(long)rb[u] * K + lane];
#pragma unroll
                for (int u = 0; u < 8; ++u) acca[0] += dq8(ta[u]);
#pragma unroll
                for (int u = 0; u < 8; ++u) accb[0] += dq8(tb[u]);
            }
            ja += 8;
            jb += 8;
        }
        for (; ja + 8 <= j1a; ja += 8) {
            int r[8];
#pragma unroll
            for (int u = 0; u < 8; ++u) r[u] = csr_src[ja + u];
            if (KL == 2) {
                unsigned tv[8];
#pragma unroll
                for (int u = 0; u < 8; ++u)
                    tv[u] = *(const unsigned short*)(h + (long)r[u] * K + lane * 2);
#pragma unroll
                for (int u = 0; u < 8; ++u) {
                    acca[0] += dq8(tv[u] & 0xff);
                    acca[1] += dq8(tv[u] >> 8);
                }
            } else {
                unsigned char tv[8];
#pragma unroll
                for (int u = 0; u < 8; ++u) tv[u] = h[(long)r[u] * K + lane];
#pragma unroll
                for (int u = 0; u < 8; ++u) acca[0] += dq8(tv[u]);
            }
        }
        for (; ja < j1a; ++ja) {  // dead with padded degrees
            int r = csr_src[ja];
            if (KL == 2) {
                unsigned u = *(const unsigned short*)(h + (long)r * K + lane * 2);
                acca[0] += dq8(u & 0xff);
                acca[1] += dq8(u >> 8);
            } else {
                acca[0] += dq8(h[(long)r * K + lane]);
            }
        }
        for (; jb + 8 <= j1b; jb += 8) {
            int r[8];
#pragma unroll
            for (int u = 0; u < 8; ++u) r[u] = csr_src[jb + u];
            if (KL == 2) {
                unsigned tv[8];
#pragma unroll
                for (int u = 0; u < 8; ++u)
                    tv[u] = *(const unsigned short*)(h + (long)r[u] * K + lane * 2);
#pragma unroll
                for (int u = 0; u < 8; ++u) {
                    accb[0] += dq8(tv[u] & 0xff);
                    accb[1] += dq8(tv[u] >> 8);
                }
            } else {
                unsigned char tv[8];
#pragma unroll
                for (int u = 0; u < 8; ++u) tv[u] = h[(long)r[u] * K + lane];
#pragma unroll
                for (int u = 0; u < 8; ++u) accb[0] += dq8(tv[u]);
            }
        }
        for (; jb < j1b; ++jb) {  // dead with padded degrees
            int r = csr_src[jb];
            if (KL == 2) {
                unsigned u = *(const unsigned short*)(h + (long)r * K + lane * 2);
                accb[0] += dq8(u & 0xff);
                accb[1] += dq8(u >> 8);
            } else {
                accb[0] += dq8(h[(long)r * K + lane]);
            }
        }
        float da = dinv[va];
        float db = dinv[vb];
        int rla = wave * 4 + pr * 2;
        if (KL == 2) {
            unsigned pa = (unsigned)bf16_rne(da * acca[0]) | ((unsigned)bf16_rne(da * acca[1]) << 16);
            unsigned pb = (unsigned)bf16_rne(db * accb[0]) | ((unsigned)bf16_rne(db * accb[1]) << 16);
            *(unsigned*)&plds[rla][lane * 2] = pa;
            *(unsigned*)&plds[rla + 1][lane * 2] = pb;
        } else {
            plds[rla][lane] = bf16_rne(da * acca[0]);
            plds[rla + 1][lane] = bf16_rne(db * accb[0]);
        }
    }
    __syncthreads();

    // ---- phase 2: MFMA (layout verified R9/R11) ----
    int quad = lane >> 4;
    int l16 = lane & 15;
    bf16x8 afr[KB];
#pragma unroll
    for (int kb = 0; kb < KB; ++kb)
        afr[kb] = *(const bf16x8*)(const void*)&plds[l16][kb * 32 + quad * 8];
#pragma unroll
    for (int fi = 0; fi < FPW; ++fi) {
        int f0 = (wave * FPW + fi) * 16;
        const unsigned short* wrow = Wt + (long)(f0 + l16) * K + quad * 8;
        f32x4 acc4 = {0.f, 0.f, 0.f, 0.f};
#pragma unroll
        for (int kb = 0; kb < KB; ++kb) {
            bf16x8 bb = *(const bf16x8*)(const void*)(wrow + kb * 32);
            acc4 = __builtin_amdgcn_mfma_f32_16x16x32_bf16(afr[kb], bb, acc4, 0, 0, 0);
        }
        float bias = b[f0 + l16];
        if (POOL) {
            int g0 = batch[m0];
            int g15 = batch[m0 + 15];
            if (g0 == g15) {  // uniform block (all but ~15 of 3125)
                float s = fmaxf(acc4[0] + bias, 0.0f);
                s += fmaxf(acc4[1] + bias, 0.0f);
                s += fmaxf(acc4[2] + bias, 0.0f);
                s += fmaxf(acc4[3] + bias, 0.0f);
                s += __shfl_xor(s, 16);
                s += __shfl_xor(s, 32);
                if (quad == 0) atomicAdd(&psum[g0 * 256 + f0 + l16], s);
            } else {  // graph boundary inside block: per-element atomics
#pragma unroll
                for (int r = 0; r < 4; ++r) {
                    int m = m0 + quad * 4 + r;
                    float val = fmaxf(acc4[r] + bias, 0.0f);
                    atomicAdd(&psum[batch[m] * 256 + f0 + l16], val);
                }
            }
        } else {
#pragma unroll
            for (int r = 0; r < 4; ++r) {
                int m = m0 + quad * 4 + r;
                float val = fmaxf(acc4[r] + bias, 0.0f);
                if (PRESCALE) val *= dinv[m] * 64.0f;  // prop pre-scale + e4m4 shift
                out[(long)m * F + f0 + l16] = (unsigned char)q8(val);
            }
        }
    }
}

// ---- final FC --------------------------------------------------------------
__global__ void k_fc(const float* __restrict__ psum, const float* __restrict__ pcnt,
                     const float* __restrict__ Wfc, const float* __restrict__ bfc,
                     float* __restrict__ out) {
    int tid = blockIdx.x * blockDim.x + threadIdx.x;
    if (tid >= NUM_GRAPHS * NUM_CLASSES) return;
    int g = tid / NUM_CLASSES;
    int c = tid % NUM_CLASSES;
    float s = 0.0f;
#pragma unroll 8
    for (int k = 0; k < 256; ++k) s = fmaf(psum[g * 256 + k], Wfc[k * NUM_CLASSES + c], s);
    float cnt = pcnt[g];
    cnt = cnt > 1.0f ? cnt : 1.0f;
    out[tid] = s / cnt + bfc[c];
}

extern "C" void kernel_launch(void* const* d_in, const int* in_sizes, int n_in,
                              void* d_out, int out_size, void* d_ws, size_t ws_size,
                              hipStream_t stream) {
    const float* x     = (const float*)d_in[0];
    const int*   ei    = (const int*)d_in[1];
    const int*   batch = (const int*)d_in[2];
    const float* W1    = (const float*)d_in[3];
    const float* b1    = (const float*)d_in[4];
    const float* W2    = (const float*)d_in[5];
    const float* b2    = (const float*)d_in[6];
    const float* W3    = (const float*)d_in[7];
    const float* b3    = (const float*)d_in[8];
    const float* Wfc   = (const float*)d_in[9];
    const float* bfc   = (const float*)d_in[10];
    float* out = (float*)d_out;

    const int* row = ei;            // src
    const int* col = ei + N_EDGES;  // dst

    // workspace layout, 16B-aligned; sentinel row at index N_NODES.
    // X/Y are unsigned-e4m4 bytes now (64 B / 128 B per node).
    float*  xs   = (float*)d_ws;                         // (N+1)*3 f32 (padded to 150004)
    float*  dinv = xs + 150004;                          // N
    float*  psum = dinv + N_NODES;                       // 16*256
    float*  pcnt = psum + NUM_GRAPHS * 256;              // 16
    unsigned char* X = (unsigned char*)(pcnt + NUM_GRAPHS);      // (N+1)*64 B
    unsigned char* Y = X + (size_t)(N_NODES + 1) * 64;           // (N+1)*128 B
    unsigned short* Wt2 = (unsigned short*)(Y + (size_t)(N_NODES + 1) * 128);  // 128*64
    unsigned short* Wt3 = Wt2 + 128 * 64;                        // 256*128
    int* degc   = (int*)(Wt3 + 256 * 128);               // 8*N (XCD-local copies)
    int* base   = degc + 8 * N_NODES;                    // 8*N (per-copy slot bases)
    int* rowptr = base + 8 * N_NODES;                    // N+1
    int* csrsrc = rowptr + N_NODES + 1;                  // CSR_CAP (padded)
    int* pos    = csrsrc + CSR_CAP;                      // E
    int* bsum   = pos + N_EDGES;                         // SCAN_BLOCKS

    hipMemsetAsync(degc, 0, 8 * N_NODES * sizeof(int), stream);
    hipMemsetAsync(psum, 0, (NUM_GRAPHS * 256 + NUM_GRAPHS) * sizeof(float), stream);
    // zero sentinel rows of X / Y (read by padded gather slots; q=0 -> 0.0)
    hipMemsetAsync(X + (size_t)N_NODES * 64, 0, 64, stream);
    hipMemsetAsync(Y + (size_t)N_NODES * 128, 0, 128, stream);

    // ---- CSR build + norms + pre-scaled x + weight casts ----
    k_deg<<<nblk(N_EDGES), 256, 0, stream>>>(col, degc, pos, N_EDGES);
    k_scan1<<<SCAN_BLOCKS, 256, 0, stream>>>(degc, rowptr, bsum, batch, pcnt, N_NODES);
    k_scan3<<<SCAN_BLOCKS, 256, 0, stream>>>(rowptr, bsum, degc, base, dinv, x, xs,
                                             csrsrc, W2, W3, Wt2, Wt3, N_NODES);
    k_fill<<<nblk(N_EDGES), 256, 0, stream>>>(row, col, base, pos, csrsrc, N_EDGES);

    // ---- layer 1 (fused prop+linear): X = q8(64*d*relu((A~x)W1+b1)) --------
    k_layer1<<<nblk(N_NODES), 256, 0, stream>>>(xs, dinv, rowptr, csrsrc, W1, b1, X, N_NODES);

    int mtiles = N_NODES / 16;  // 3125, exact

    // ---- layer 2 fused: Y = q8(64*d*relu((A~-apply X) W2 + b2)) ------------
    k_fused<64, 128, true, false><<<mtiles, 256, 0, stream>>>(
        X, dinv, rowptr, csrsrc, Wt2, b2, Y, batch, psum, N_NODES);

    // ---- layer 3 fused + POOL: psum += relu((A~-apply Y) W3 + b3) ----------
    k_fused<128, 256, false, true><<<mtiles, 256, 0, stream>>>(
        Y, dinv, rowptr, csrsrc, Wt3, b3, (unsigned char*)nullptr, batch, psum, N_NODES);

    // ---- FC ----
    k_fc<<<nblk(NUM_GRAPHS * NUM_CLASSES), 256, 0, stream>>>(psum, pcnt, Wfc, bfc, out);
}